// Round 2
// baseline (253.234 us; speedup 1.0000x reference)
//
#include <hip/hip_runtime.h>
#include <math.h>

#define BB   2
#define DD   192
#define LL   4096
#define KK   8
#define NN   16
#define RR   6
#define C38  38
#define CPAD 40
#define NCH  64   // chunks per channel
#define CLEN (LL / NCH)
#define NCHAN (BB * KK * DD)   // 3072 channels total

__device__ __forceinline__ float fexp2(float x) { return __builtin_amdgcn_exp2f(x); }
__device__ __forceinline__ float flog2(float x) { return __builtin_amdgcn_logf(x); }

__device__ __forceinline__ float softplus_f(float x) {
  return fmaxf(x, 0.f) + 0.69314718f * flog2(1.f + fexp2(-1.44269504f * fabsf(x)));
}

// xs[b,k,d,l] = x[b,d,src_index(k,l)]
__device__ __forceinline__ int src_index(int k, int l) {
  int ll = (k & 2) ? (LL - 1 - l) : l;
  int kb = k & 5;
  if (kb == 0) return ll;
  int h = ll & 63, w = ll >> 6;
  if (kb == 1) return (h << 6) + w;
  if (kb == 4) return (h << 6) + ((h + w) & 63);
  return (h << 6) + ((w - h) & 63);
}

__global__ __launch_bounds__(256) void transpose_x(const float* __restrict__ x,
                                                   float* __restrict__ xT) {
  __shared__ float tile[32][33];
  int b  = blockIdx.z;
  int p0 = blockIdx.x * 32;
  int d0 = blockIdx.y * 32;
  int tx = threadIdx.x, ty = threadIdx.y;
  #pragma unroll
  for (int i = 0; i < 32; i += 8)
    tile[ty + i][tx] = x[((size_t)(b * DD + d0 + ty + i)) * LL + p0 + tx];
  __syncthreads();
  #pragma unroll
  for (int i = 0; i < 32; i += 8)
    xT[((size_t)(b * LL + p0 + ty + i)) * DD + d0 + tx] = tile[tx][ty + i];
}

// x_dbl[b,k,l,c] = sum_d xT[b, src_k(l), d] * W[k,c,d];  d split across 2 halves
__global__ __launch_bounds__(256) void proj_kernel(const float* __restrict__ xT,
                                                   const float* __restrict__ W,
                                                   float* __restrict__ xdbl) {
  int k = blockIdx.y, b = blockIdx.z;
  int tx = threadIdx.x;
  int lloc = tx & 127, half = tx >> 7;
  int l = blockIdx.x * 128 + lloc;
  __shared__ __align__(16) float sm[DD * CPAD];  // 30720 B; reused for partials
  for (int i = tx; i < C38 * DD; i += 256) {
    int c = i / DD, dq = i - c * DD;
    sm[dq * CPAD + c] = W[(k * C38 + c) * DD + dq];
  }
  for (int dq = tx; dq < DD; dq += 256) { sm[dq * CPAD + 38] = 0.f; sm[dq * CPAD + 39] = 0.f; }
  __syncthreads();

  int p = src_index(k, l);
  const float4* xrow4 = (const float4*)(xT + ((size_t)b * LL + p) * DD) + half * 24;
  const float* wbase = sm + half * 96 * CPAD;
  float4 acc[10];
  #pragma unroll
  for (int c = 0; c < 10; ++c) acc[c] = make_float4(0.f, 0.f, 0.f, 0.f);

  for (int d4 = 0; d4 < 24; ++d4) {
    float4 xv = xrow4[d4];
    #pragma unroll
    for (int s = 0; s < 4; ++s) {
      float xs = (s == 0) ? xv.x : (s == 1) ? xv.y : (s == 2) ? xv.z : xv.w;
      const float4* w4 = (const float4*)(wbase + (d4 * 4 + s) * CPAD);
      #pragma unroll
      for (int c = 0; c < 10; ++c) {
        float4 wv = w4[c];
        acc[c].x = fmaf(wv.x, xs, acc[c].x);
        acc[c].y = fmaf(wv.y, xs, acc[c].y);
        acc[c].z = fmaf(wv.z, xs, acc[c].z);
        acc[c].w = fmaf(wv.w, xs, acc[c].w);
      }
    }
  }
  __syncthreads();  // Wt no longer needed; reuse sm for partials (128*41 <= 7680)
  if (half == 1) {
    float* pr = sm + lloc * 41;
    const float* af = (const float*)acc;
    #pragma unroll
    for (int c = 0; c < 38; ++c) pr[c] = af[c];
  }
  __syncthreads();
  if (half == 0) {
    const float* pr = sm + lloc * 41;
    float* af = (float*)acc;
    #pragma unroll
    for (int c = 0; c < 38; ++c) af[c] += pr[c];
    float* orow = xdbl + ((size_t)((b * KK + k) * LL) + l) * CPAD;
    float4* o4 = (float4*)orow;
    #pragma unroll
    for (int c = 0; c < 9; ++c) o4[c] = acc[c];
    orow[36] = acc[9].x;
    orow[37] = acc[9].y;
  }
}

// Scan: wave = 32 d x 2 n-halves; block (64,6) covers 192 d of ONE chunk.
// xdbl rows for the chunk are staged into LDS once (reordered for alignment:
// floats [0..5]=dt-rank, [8..23]=B, [24..39]=C). uu gather prefetched 4-7 steps.
// Phase A (FINAL=false): S = sum softplus, q = local final h (h0=0).
// Phase C (FINAL=true):  recurrence from stitched h0; fused cross_merge scatter-add.
template <bool FINAL>
__global__ __launch_bounds__(384, 4) void scan_kernel(
    const float* __restrict__ xT, const float* __restrict__ xdbl,
    const float* __restrict__ A_logs, const float* __restrict__ dtw,
    const float* __restrict__ dtb, const float* __restrict__ Ds,
    float* __restrict__ Sarr, float* __restrict__ Qarr, float* __restrict__ Y) {
  constexpr int ROWF  = FINAL ? 40 : 24;   // floats per LDS row
  constexpr int ROWF2 = ROWF / 2;          // float2 per LDS row
  constexpr int SRCF2 = FINAL ? 19 : 11;   // float2 copied per source row

  __shared__ __align__(16) float rows[CLEN * ROWF];

  const int lane  = threadIdx.x;        // 0..63
  const int ng    = lane >> 5;          // n-half
  const int dd    = threadIdx.y;        // 0..5
  const int tid   = dd * 64 + lane;
  const int bk    = blockIdx.x;         // 0..15
  const int chunk = blockIdx.y;         // 0..NCH-1
  const int b = bk >> 3, k = bk & 7;
  const int d  = dd * 32 + (lane & 31);
  const int kd = k * DD + d;
  const int ch = bk * DD + d;
  const int l0 = chunk * CLEN;

  // ---- stage chunk's xdbl rows into LDS (coalesced float2, reordered) ----
  {
    const float2* src2 = (const float2*)(xdbl + ((size_t)(bk * LL) + l0) * CPAD);
    float2* dst2 = (float2*)rows;
    for (int i = tid; i < CLEN * SRCF2; i += 384) {
      int r = i / SRCF2, c = i - r * SRCF2;
      dst2[r * ROWF2 + c + (c >= 3)] = src2[r * (CPAD / 2) + c];
    }
  }

  // ---- per-thread parameters (overlap with staging latency) ----
  float An2[8];
  {
    const float* ap = A_logs + (size_t)kd * NN + ng * 8;
    #pragma unroll
    for (int j = 0; j < 8; ++j) An2[j] = -__expf(ap[j]) * 1.44269504f;
  }
  float wdt[RR];
  #pragma unroll
  for (int r = 0; r < RR; ++r) wdt[r] = dtw[kd * RR + r];
  const float bias = dtb[kd];
  const float dval = FINAL ? Ds[kd] : 0.f;

  float h[8];
  if constexpr (FINAL) {
    const float* h0p = Qarr + ((size_t)chunk * NCHAN + ch) * NN + ng * 8;
    #pragma unroll
    for (int j = 0; j < 8; ++j) h[j] = h0p[j];
  } else {
    #pragma unroll
    for (int j = 0; j < 8; ++j) h[j] = 0.f;
  }

  const float* xTb = xT + (size_t)b * LL * DD + d;
  float S = 0.f;

  __syncthreads();

  auto STEP = [&](int t, int p, float u) {
    const float* row = rows + t * ROWF;
    float dts = bias;
    dts = fmaf(row[0], wdt[0], dts);
    dts = fmaf(row[1], wdt[1], dts);
    dts = fmaf(row[2], wdt[2], dts);
    dts = fmaf(row[3], wdt[3], dts);
    dts = fmaf(row[4], wdt[4], dts);
    dts = fmaf(row[5], wdt[5], dts);
    float spv = softplus_f(dts);
    float du = spv * u;
    const float4* bq = (const float4*)(row + 8 + ng * 8);
    float4 b0 = bq[0], b1 = bq[1];
    float Bvv[8] = {b0.x, b0.y, b0.z, b0.w, b1.x, b1.y, b1.z, b1.w};
    #pragma unroll
    for (int j = 0; j < 8; ++j) {
      float e = fexp2(spv * An2[j]);
      h[j] = fmaf(h[j], e, du * Bvv[j]);
    }
    if constexpr (FINAL) {
      const float4* cq = (const float4*)(row + 24 + ng * 8);
      float4 c0 = cq[0], c1 = cq[1];
      float Cvv[8] = {c0.x, c0.y, c0.z, c0.w, c1.x, c1.y, c1.z, c1.w};
      float y = 0.f;
      #pragma unroll
      for (int j = 0; j < 8; ++j) y = fmaf(h[j], Cvv[j], y);
      y += __shfl_xor(y, 32, 64);
      if (ng == 0) {
        atomicAdd(&Y[(size_t)(b * LL + p) * DD + d], fmaf(u, dval, y));
      }
    } else {
      S += spv;
    }
  };

  // ---- main loop: two 4-wide uu-prefetch groups, distance 4-7 steps ----
  int ppA[4], ppB[4];
  float uuA[4], uuB[4];
  #pragma unroll
  for (int s = 0; s < 4; ++s) {
    int p = src_index(k, l0 + s);
    ppA[s] = p; uuA[s] = xTb[(size_t)p * DD];
  }
  for (int tb = 0; tb < CLEN; tb += 8) {
    #pragma unroll
    for (int s = 0; s < 4; ++s) {
      int p = src_index(k, l0 + tb + 4 + s);
      ppB[s] = p; uuB[s] = xTb[(size_t)p * DD];
    }
    #pragma unroll
    for (int s = 0; s < 4; ++s) STEP(tb + s, ppA[s], uuA[s]);
    int nb = (tb + 8 < CLEN) ? tb + 8 : 0;   // dummy reload on last iter (harmless)
    #pragma unroll
    for (int s = 0; s < 4; ++s) {
      int p = src_index(k, l0 + nb + s);
      ppA[s] = p; uuA[s] = xTb[(size_t)p * DD];
    }
    #pragma unroll
    for (int s = 0; s < 4; ++s) STEP(tb + 4 + s, ppB[s], uuB[s]);
  }

  if constexpr (!FINAL) {
    if (ng == 0) Sarr[(size_t)chunk * NCHAN + ch] = S;
    float* qp = Qarr + ((size_t)chunk * NCHAN + ch) * NN + ng * 8;
    #pragma unroll
    for (int j = 0; j < 8; ++j) qp[j] = h[j];
  }
}

// Wave-parallel stitch: one wave per (ch, n); shuffle scan of (P,q) composition.
// Layout: Sarr[chunk][ch], Qarr[chunk][ch][16] (aligned, coalesced in scan phases).
__global__ __launch_bounds__(256) void stitch_kernel(float* __restrict__ Sarr,
                                                     float* __restrict__ Qarr,
                                                     const float* __restrict__ A_logs) {
  int lane = threadIdx.x & 63;                      // chunk index
  int gw = (blockIdx.x * 256 + threadIdx.x) >> 6;   // 0..49151 = ch*16+n
  int chn = gw >> 4, n = gw & 15;
  int kd = chn % (KK * DD);
  float An2 = -__expf(A_logs[(size_t)kd * NN + n]) * 1.44269504f;

  float P = fexp2(An2 * Sarr[(size_t)lane * NCHAN + chn]);
  float q = Qarr[((size_t)lane * NCHAN + chn) * NN + n];

  float Pt = P, qt = q;
  #pragma unroll
  for (int off = 1; off < 64; off <<= 1) {
    float Pp = __shfl_up(Pt, off, 64);
    float qp = __shfl_up(qt, off, 64);
    if (lane >= off) { qt = fmaf(Pt, qp, qt); Pt *= Pp; }
  }
  float hx = __shfl_up(qt, 1, 64);
  if (lane == 0) hx = 0.f;
  Qarr[((size_t)lane * NCHAN + chn) * NN + n] = hx;  // h0 for this chunk
}

__global__ __launch_bounds__(256) void ln_kernel(const float* __restrict__ Y,
                                                 const float* __restrict__ lw,
                                                 const float* __restrict__ lb,
                                                 float* __restrict__ out) {
  int lane = threadIdx.x & 63;
  int row = blockIdx.x * 4 + (threadIdx.x >> 6);
  const float* yr = Y + (size_t)row * DD;
  float v0 = yr[lane], v1 = yr[lane + 64], v2 = yr[lane + 128];
  float s1 = v0 + v1 + v2;
  float s2 = v0 * v0 + v1 * v1 + v2 * v2;
  #pragma unroll
  for (int m = 32; m >= 1; m >>= 1) {
    s1 += __shfl_xor(s1, m, 64);
    s2 += __shfl_xor(s2, m, 64);
  }
  float mu = s1 * (1.f / DD);
  float var = s2 * (1.f / DD) - mu * mu;
  float inv = rsqrtf(var + 1e-5f);
  float* orow = out + (size_t)row * DD;
  orow[lane]       = (v0 - mu) * inv * lw[lane]       + lb[lane];
  orow[lane + 64]  = (v1 - mu) * inv * lw[lane + 64]  + lb[lane + 64];
  orow[lane + 128] = (v2 - mu) * inv * lw[lane + 128] + lb[lane + 128];
}

extern "C" void kernel_launch(void* const* d_in, const int* in_sizes, int n_in,
                              void* d_out, int out_size, void* d_ws, size_t ws_size,
                              hipStream_t stream) {
  const float* x      = (const float*)d_in[0];
  const float* xpw    = (const float*)d_in[1];
  const float* dtw    = (const float*)d_in[2];
  const float* dtb    = (const float*)d_in[3];
  const float* A_logs = (const float*)d_in[4];
  const float* Ds     = (const float*)d_in[5];
  const float* ln_w   = (const float*)d_in[6];
  const float* ln_b   = (const float*)d_in[7];
  float* out = (float*)d_out;

  float* ws   = (float*)d_ws;
  float* xT   = ws;                    // B*L*D          = 1572864 floats
  float* xdbl = xT + 1572864;          // B*K*L*CPAD     = 2621440
  float* Y    = xdbl + 2621440;        // B*L*D          = 1572864
  float* Sarr = Y + 1572864;           // NCH*NCHAN      = 196608
  float* Qarr = Sarr + 196608;         // NCH*NCHAN*16   = 3145728

  hipMemsetAsync(Y, 0, 1572864 * sizeof(float), stream);
  transpose_x<<<dim3(LL / 32, DD / 32, BB), dim3(32, 8), 0, stream>>>(x, xT);
  proj_kernel<<<dim3(LL / 128, KK, BB), 256, 0, stream>>>(xT, xpw, xdbl);
  scan_kernel<false><<<dim3(BB * KK, NCH), dim3(64, 6), 0, stream>>>(
      xT, xdbl, A_logs, dtw, dtb, Ds, Sarr, Qarr, Y);
  stitch_kernel<<<(NCHAN * 16 * 64) / 256, 256, 0, stream>>>(Sarr, Qarr, A_logs);
  scan_kernel<true><<<dim3(BB * KK, NCH), dim3(64, 6), 0, stream>>>(
      xT, xdbl, A_logs, dtw, dtb, Ds, Sarr, Qarr, Y);
  ln_kernel<<<(BB * LL) / 4, 256, 0, stream>>>(Y, ln_w, ln_b, out);
}

// Round 3
// 221.812 us; speedup vs baseline: 1.1417x; 1.1417x over previous
//
#include <hip/hip_runtime.h>
#include <math.h>

#define BB   2
#define DD   192
#define LL   4096
#define KK   8
#define NN   16
#define RR   6
#define C38  38
#define CPAD 40
#define NCH  64   // chunks per channel
#define CLEN (LL / NCH)
#define NCHAN (BB * KK * DD)   // 3072 channels total

__device__ __forceinline__ float fexp2(float x) { return __builtin_amdgcn_exp2f(x); }
__device__ __forceinline__ float flog2(float x) { return __builtin_amdgcn_logf(x); }

__device__ __forceinline__ float softplus_f(float x) {
  return fmaxf(x, 0.f) + 0.69314718f * flog2(1.f + fexp2(-1.44269504f * fabsf(x)));
}

// xs[b,k,d,l] = x[b,d,src_index(k,l)]
__device__ __forceinline__ int src_index(int k, int l) {
  int ll = (k & 2) ? (LL - 1 - l) : l;
  int kb = k & 5;
  if (kb == 0) return ll;
  int h = ll & 63, w = ll >> 6;
  if (kb == 1) return (h << 6) + w;
  if (kb == 4) return (h << 6) + ((h + w) & 63);
  return (h << 6) + ((w - h) & 63);
}

__global__ __launch_bounds__(256) void transpose_x(const float* __restrict__ x,
                                                   float* __restrict__ xT) {
  __shared__ float tile[32][33];
  int b  = blockIdx.z;
  int p0 = blockIdx.x * 32;
  int d0 = blockIdx.y * 32;
  int tx = threadIdx.x, ty = threadIdx.y;
  #pragma unroll
  for (int i = 0; i < 32; i += 8)
    tile[ty + i][tx] = x[((size_t)(b * DD + d0 + ty + i)) * LL + p0 + tx];
  __syncthreads();
  #pragma unroll
  for (int i = 0; i < 32; i += 8)
    xT[((size_t)(b * LL + p0 + ty + i)) * DD + d0 + tx] = tile[tx][ty + i];
}

// x_dbl[b,k,l,c] = sum_d xT[b, src_k(l), d] * W[k,c,d];  d split across 2 halves
__global__ __launch_bounds__(256) void proj_kernel(const float* __restrict__ xT,
                                                   const float* __restrict__ W,
                                                   float* __restrict__ xdbl) {
  int k = blockIdx.y, b = blockIdx.z;
  int tx = threadIdx.x;
  int lloc = tx & 127, half = tx >> 7;
  int l = blockIdx.x * 128 + lloc;
  __shared__ __align__(16) float sm[DD * CPAD];  // 30720 B; reused for partials
  for (int i = tx; i < C38 * DD; i += 256) {
    int c = i / DD, dq = i - c * DD;
    sm[dq * CPAD + c] = W[(k * C38 + c) * DD + dq];
  }
  for (int dq = tx; dq < DD; dq += 256) { sm[dq * CPAD + 38] = 0.f; sm[dq * CPAD + 39] = 0.f; }
  __syncthreads();

  int p = src_index(k, l);
  const float4* xrow4 = (const float4*)(xT + ((size_t)b * LL + p) * DD) + half * 24;
  const float* wbase = sm + half * 96 * CPAD;
  float4 acc[10];
  #pragma unroll
  for (int c = 0; c < 10; ++c) acc[c] = make_float4(0.f, 0.f, 0.f, 0.f);

  for (int d4 = 0; d4 < 24; ++d4) {
    float4 xv = xrow4[d4];
    #pragma unroll
    for (int s = 0; s < 4; ++s) {
      float xs = (s == 0) ? xv.x : (s == 1) ? xv.y : (s == 2) ? xv.z : xv.w;
      const float4* w4 = (const float4*)(wbase + (d4 * 4 + s) * CPAD);
      #pragma unroll
      for (int c = 0; c < 10; ++c) {
        float4 wv = w4[c];
        acc[c].x = fmaf(wv.x, xs, acc[c].x);
        acc[c].y = fmaf(wv.y, xs, acc[c].y);
        acc[c].z = fmaf(wv.z, xs, acc[c].z);
        acc[c].w = fmaf(wv.w, xs, acc[c].w);
      }
    }
  }
  __syncthreads();  // Wt no longer needed; reuse sm for partials (128*41 <= 7680)
  if (half == 1) {
    float* pr = sm + lloc * 41;
    const float* af = (const float*)acc;
    #pragma unroll
    for (int c = 0; c < 38; ++c) pr[c] = af[c];
  }
  __syncthreads();
  if (half == 0) {
    const float* pr = sm + lloc * 41;
    float* af = (float*)acc;
    #pragma unroll
    for (int c = 0; c < 38; ++c) af[c] += pr[c];
    float* orow = xdbl + ((size_t)((b * KK + k) * LL) + l) * CPAD;
    float4* o4 = (float4*)orow;
    #pragma unroll
    for (int c = 0; c < 9; ++c) o4[c] = acc[c];
    orow[36] = acc[9].x;
    orow[37] = acc[9].y;
  }
}

// Scan: wave = 32 d x 2 n-halves; block (64,6) covers 192 d of ONE chunk.
// xdbl rows for the chunk are staged into LDS once (reordered for alignment:
// floats [0..5]=dt-rank, [8..23]=B, [24..39]=C). uu gather prefetched 4-7 steps.
// Phase A (FINAL=false): S = sum softplus, q = local final h (h0=0).
// Phase C (FINAL=true):  recurrence from stitched h0; fused cross_merge scatter-add.
template <bool FINAL>
__global__ __launch_bounds__(384, 4) void scan_kernel(
    const float* __restrict__ xT, const float* __restrict__ xdbl,
    const float* __restrict__ A_logs, const float* __restrict__ dtw,
    const float* __restrict__ dtb, const float* __restrict__ Ds,
    float* __restrict__ Sarr, float* __restrict__ Qarr, float* __restrict__ Y) {
  constexpr int ROWF  = FINAL ? 40 : 24;   // floats per LDS row
  constexpr int ROWF2 = ROWF / 2;          // float2 per LDS row
  constexpr int SRCF2 = FINAL ? 19 : 11;   // float2 copied per source row

  __shared__ __align__(16) float rows[CLEN * ROWF];

  const int lane  = threadIdx.x;        // 0..63
  const int ng    = lane >> 5;          // n-half
  const int dd    = threadIdx.y;        // 0..5
  const int tid   = dd * 64 + lane;
  const int bk    = blockIdx.x;         // 0..15
  const int chunk = blockIdx.y;         // 0..NCH-1
  const int b = bk >> 3, k = bk & 7;
  const int d  = dd * 32 + (lane & 31);
  const int kd = k * DD + d;
  const int ch = bk * DD + d;
  const int l0 = chunk * CLEN;

  // ---- stage chunk's xdbl rows into LDS (coalesced float2, reordered) ----
  {
    const float2* src2 = (const float2*)(xdbl + ((size_t)(bk * LL) + l0) * CPAD);
    float2* dst2 = (float2*)rows;
    for (int i = tid; i < CLEN * SRCF2; i += 384) {
      int r = i / SRCF2, c = i - r * SRCF2;
      dst2[r * ROWF2 + c + (c >= 3)] = src2[r * (CPAD / 2) + c];
    }
  }

  // ---- per-thread parameters (overlap with staging latency) ----
  float An2[8];
  {
    const float* ap = A_logs + (size_t)kd * NN + ng * 8;
    #pragma unroll
    for (int j = 0; j < 8; ++j) An2[j] = -__expf(ap[j]) * 1.44269504f;
  }
  float wdt[RR];
  #pragma unroll
  for (int r = 0; r < RR; ++r) wdt[r] = dtw[kd * RR + r];
  const float bias = dtb[kd];
  const float dval = FINAL ? Ds[kd] : 0.f;

  float h[8];
  if constexpr (FINAL) {
    const float* h0p = Qarr + ((size_t)chunk * NCHAN + ch) * NN + ng * 8;
    #pragma unroll
    for (int j = 0; j < 8; ++j) h[j] = h0p[j];
  } else {
    #pragma unroll
    for (int j = 0; j < 8; ++j) h[j] = 0.f;
  }

  const float* xTb = xT + (size_t)b * LL * DD + d;
  float S = 0.f;

  __syncthreads();

  auto STEP = [&](int t, int p, float u) {
    const float* row = rows + t * ROWF;
    float dts = bias;
    dts = fmaf(row[0], wdt[0], dts);
    dts = fmaf(row[1], wdt[1], dts);
    dts = fmaf(row[2], wdt[2], dts);
    dts = fmaf(row[3], wdt[3], dts);
    dts = fmaf(row[4], wdt[4], dts);
    dts = fmaf(row[5], wdt[5], dts);
    float spv = softplus_f(dts);
    float du = spv * u;
    const float4* bq = (const float4*)(row + 8 + ng * 8);
    float4 b0 = bq[0], b1 = bq[1];
    float Bvv[8] = {b0.x, b0.y, b0.z, b0.w, b1.x, b1.y, b1.z, b1.w};
    #pragma unroll
    for (int j = 0; j < 8; ++j) {
      float e = fexp2(spv * An2[j]);
      h[j] = fmaf(h[j], e, du * Bvv[j]);
    }
    if constexpr (FINAL) {
      const float4* cq = (const float4*)(row + 24 + ng * 8);
      float4 c0 = cq[0], c1 = cq[1];
      float Cvv[8] = {c0.x, c0.y, c0.z, c0.w, c1.x, c1.y, c1.z, c1.w};
      float y = 0.f;
      #pragma unroll
      for (int j = 0; j < 8; ++j) y = fmaf(h[j], Cvv[j], y);
      y += __shfl_xor(y, 32, 64);
      if (ng == 0) {
        atomicAdd(&Y[(size_t)(b * LL + p) * DD + d], fmaf(u, dval, y));
      }
    } else {
      S += spv;
    }
  };

  // ---- main loop: two 4-wide uu-prefetch groups, distance 4-7 steps ----
  int ppA[4], ppB[4];
  float uuA[4], uuB[4];
  #pragma unroll
  for (int s = 0; s < 4; ++s) {
    int p = src_index(k, l0 + s);
    ppA[s] = p; uuA[s] = xTb[(size_t)p * DD];
  }
  for (int tb = 0; tb < CLEN; tb += 8) {
    #pragma unroll
    for (int s = 0; s < 4; ++s) {
      int p = src_index(k, l0 + tb + 4 + s);
      ppB[s] = p; uuB[s] = xTb[(size_t)p * DD];
    }
    #pragma unroll
    for (int s = 0; s < 4; ++s) STEP(tb + s, ppA[s], uuA[s]);
    int nb = (tb + 8 < CLEN) ? tb + 8 : 0;   // dummy reload on last iter (harmless)
    #pragma unroll
    for (int s = 0; s < 4; ++s) {
      int p = src_index(k, l0 + nb + s);
      ppA[s] = p; uuA[s] = xTb[(size_t)p * DD];
    }
    #pragma unroll
    for (int s = 0; s < 4; ++s) STEP(tb + 4 + s, ppB[s], uuB[s]);
  }

  if constexpr (!FINAL) {
    if (ng == 0) Sarr[(size_t)chunk * NCHAN + ch] = S;
    float* qp = Qarr + ((size_t)chunk * NCHAN + ch) * NN + ng * 8;
    #pragma unroll
    for (int j = 0; j < 8; ++j) qp[j] = h[j];
  }
}

// Stitch: one THREAD per (ch, n); serial scan over the 64 chunks with an
// 8-deep register prefetch pipeline. With t = ch*16+n, per-chunk q addresses
// are consecutive across threads (fully coalesced); S is a 16-lane broadcast.
// Writes the exclusive prefix h0 back in place (Qarr[c] <- h_before_c).
__global__ __launch_bounds__(256) void stitch_kernel(const float* __restrict__ Sarr,
                                                     float* __restrict__ Qarr,
                                                     const float* __restrict__ A_logs) {
  const int t  = blockIdx.x * 256 + threadIdx.x;  // 0..49151 = ch*16 + n
  const int ch = t >> 4, n = t & 15;
  const int kd = ch % (KK * DD);
  const float An2 = -__expf(A_logs[(size_t)kd * NN + n]) * 1.44269504f;

  float q[8], Sv[8];
  #pragma unroll
  for (int i = 0; i < 8; ++i) {
    q[i]  = Qarr[(size_t)i * (NCHAN * NN) + t];
    Sv[i] = Sarr[(size_t)i * NCHAN + ch];
  }
  float h = 0.f;
  for (int cb = 0; cb < NCH; cb += 8) {
    #pragma unroll
    for (int i = 0; i < 8; ++i) {
      const int c = cb + i;
      Qarr[(size_t)c * (NCHAN * NN) + t] = h;          // h0 for chunk c
      h = fmaf(fexp2(An2 * Sv[i]), h, q[i]);
      const int cn = c + 8;
      if (cn < NCH) {
        q[i]  = Qarr[(size_t)cn * (NCHAN * NN) + t];
        Sv[i] = Sarr[(size_t)cn * NCHAN + ch];
      }
    }
  }
}

__global__ __launch_bounds__(256) void ln_kernel(const float* __restrict__ Y,
                                                 const float* __restrict__ lw,
                                                 const float* __restrict__ lb,
                                                 float* __restrict__ out) {
  int lane = threadIdx.x & 63;
  int row = blockIdx.x * 4 + (threadIdx.x >> 6);
  const float* yr = Y + (size_t)row * DD;
  float v0 = yr[lane], v1 = yr[lane + 64], v2 = yr[lane + 128];
  float s1 = v0 + v1 + v2;
  float s2 = v0 * v0 + v1 * v1 + v2 * v2;
  #pragma unroll
  for (int m = 32; m >= 1; m >>= 1) {
    s1 += __shfl_xor(s1, m, 64);
    s2 += __shfl_xor(s2, m, 64);
  }
  float mu = s1 * (1.f / DD);
  float var = s2 * (1.f / DD) - mu * mu;
  float inv = rsqrtf(var + 1e-5f);
  float* orow = out + (size_t)row * DD;
  orow[lane]       = (v0 - mu) * inv * lw[lane]       + lb[lane];
  orow[lane + 64]  = (v1 - mu) * inv * lw[lane + 64]  + lb[lane + 64];
  orow[lane + 128] = (v2 - mu) * inv * lw[lane + 128] + lb[lane + 128];
}

extern "C" void kernel_launch(void* const* d_in, const int* in_sizes, int n_in,
                              void* d_out, int out_size, void* d_ws, size_t ws_size,
                              hipStream_t stream) {
  const float* x      = (const float*)d_in[0];
  const float* xpw    = (const float*)d_in[1];
  const float* dtw    = (const float*)d_in[2];
  const float* dtb    = (const float*)d_in[3];
  const float* A_logs = (const float*)d_in[4];
  const float* Ds     = (const float*)d_in[5];
  const float* ln_w   = (const float*)d_in[6];
  const float* ln_b   = (const float*)d_in[7];
  float* out = (float*)d_out;

  float* ws   = (float*)d_ws;
  float* xT   = ws;                    // B*L*D          = 1572864 floats
  float* xdbl = xT + 1572864;          // B*K*L*CPAD     = 2621440
  float* Y    = xdbl + 2621440;        // B*L*D          = 1572864
  float* Sarr = Y + 1572864;           // NCH*NCHAN      = 196608
  float* Qarr = Sarr + 196608;         // NCH*NCHAN*16   = 3145728

  hipMemsetAsync(Y, 0, 1572864 * sizeof(float), stream);
  transpose_x<<<dim3(LL / 32, DD / 32, BB), dim3(32, 8), 0, stream>>>(x, xT);
  proj_kernel<<<dim3(LL / 128, KK, BB), 256, 0, stream>>>(xT, xpw, xdbl);
  scan_kernel<false><<<dim3(BB * KK, NCH), dim3(64, 6), 0, stream>>>(
      xT, xdbl, A_logs, dtw, dtb, Ds, Sarr, Qarr, Y);
  stitch_kernel<<<(NCHAN * NN) / 256, 256, 0, stream>>>(Sarr, Qarr, A_logs);
  scan_kernel<true><<<dim3(BB * KK, NCH), dim3(64, 6), 0, stream>>>(
      xT, xdbl, A_logs, dtw, dtb, Ds, Sarr, Qarr, Y);
  ln_kernel<<<(BB * LL) / 4, 256, 0, stream>>>(Y, ln_w, ln_b, out);
}